// Round 4
// baseline (206.790 us; speedup 1.0000x reference)
//
#include <hip/hip_runtime.h>

#define IMG_H 224
#define IMG_W 224
#define HW (IMG_H * IMG_W)   // 50176 (divisible by 8)
#define HWB (HW / 8)         // 6272 selbit bytes per image
#define NUM_ROWS 159
#define NUM_COLS 1024
#define BATCH 128
#define OVF_CAP 4096
#define MAXC 11              // static chunks cover 704 >= max ring (~703); n>704 -> dyn slow path
#define NBUCK 512            // counting-sort buckets; bucket = floor(val*512), exact & monotone
#define NHWORDS (NBUCK / 2)  // u32 words, 2 packed u16 counters each
#define WPL (NHWORDS / 64)   // 4 hist words (8 buckets) owned per lane

// Exact integer sqrt (v <= ~25k here, f32 sqrt + fixup loops).
__device__ __forceinline__ int isqrt_i(int v) {
    int u = (int)sqrtf((float)v);
    while (u > 0 && u * u > v) --u;
    while ((u + 1) * (u + 1) <= v) ++u;
    return u;
}

// Compiler + wave-order fence for wave-private LDS (DS pipe is in-order per
// wave; the asm stops compiler reordering and drains lgkm before reuse).
__device__ __forceinline__ void lds_fence() {
    asm volatile("s_waitcnt lgkmcnt(0)" ::: "memory");
}

// ---------------------------------------------------------------------------
// Fused pre-pass (R9): blocks [0,159) build the ring tables (verified R3-R5
// analytic form); blocks [159,...) do the coalesced out=img copy + selbit
// pack (R8). Independent work fused to save one launch gap.
// ---------------------------------------------------------------------------
__global__ __launch_bounds__(256) void pre_pass(
    const float4* __restrict__ img4, const float4* __restrict__ mask4,
    float4* __restrict__ out4, unsigned char* __restrict__ selb,
    unsigned short* __restrict__ ring_pix, int* __restrict__ ring_cnt,
    int* __restrict__ ovf_cnt) {
    const int bid = blockIdx.x;
    const int tid = threadIdx.x;
    __shared__ int scnt[256];

    if (bid < NUM_ROWS) {
        // ---- ring build: round(sqrt(dx^2+dy^2)) == d
        //      <=> Araw <= dx^2+dy^2 <= d^2+d, Araw = (d==0 ? 0 : d^2-d+1)
        const int d = bid;
        if (d == 0 && tid == 0) ovf_cnt[0] = 0;
        int cnt = 0;
        int x0l = 0, x1l = -1, x0r = 0, x1r = -1;
        if (tid < IMG_H) {
            const int dy = tid - 112;
            const int Araw = (d == 0) ? 0 : (d * d - d + 1);
            int A = Araw - dy * dy;
            if (A < 0) A = 0;
            const int B = d * d + d - dy * dy;
            if (B >= 0) {
                const int hi = isqrt_i(B);
                int lo = isqrt_i(A);
                if (lo * lo < A) ++lo;
                if (lo <= hi) {
                    if (lo == 0) {
                        x0l = 112 - min(hi, 112);
                        x1l = 112 + min(hi, 111);
                    } else {
                        x0l = 112 - min(hi, 112);
                        x1l = 112 - lo;
                        x0r = 112 + lo;
                        x1r = 112 + min(hi, 111);
                    }
                    cnt = max(0, x1l - x0l + 1) + max(0, x1r - x0r + 1);
                }
            }
        }
        scnt[tid] = cnt;
        __syncthreads();
        for (int off = 1; off < 256; off <<= 1) {
            const int mine = scnt[tid];
            const int add = (tid >= off) ? scnt[tid - off] : 0;
            __syncthreads();
            scnt[tid] = mine + add;
            __syncthreads();
        }
        if (tid < IMG_H && cnt > 0) {
            int j = d * NUM_COLS + (scnt[tid] - cnt);
            const int rowbase = tid * IMG_W;
            for (int x = x0l; x <= x1l; ++x) ring_pix[j++] = (unsigned short)(rowbase + x);
            for (int x = x0r; x <= x1r; ++x) ring_pix[j++] = (unsigned short)(rowbase + x);
        }
        if (tid == 255) ring_cnt[d] = scnt[255];
    } else {
        // ---- coalesced copy + selbit pack (8 px/thread)
        const int t = (bid - NUM_ROWS) * 256 + tid;  // < BATCH*HW/8
        const float4 i0 = img4[2 * t];
        const float4 i1 = img4[2 * t + 1];
        const float4 m0 = mask4[2 * t];
        const float4 m1 = mask4[2 * t + 1];
        out4[2 * t] = i0;
        out4[2 * t + 1] = i1;
        const unsigned by = (m0.x < 0.5f ? 1u : 0u) | (m0.y < 0.5f ? 2u : 0u) |
                            (m0.z < 0.5f ? 4u : 0u) | (m0.w < 0.5f ? 8u : 0u) |
                            (m1.x < 0.5f ? 16u : 0u) | (m1.y < 0.5f ? 32u : 0u) |
                            (m1.z < 0.5f ? 64u : 0u) | (m1.w < 0.5f ? 128u : 0u);
        selb[t] = (unsigned char)by;
    }
}

// In-LDS insertion sort of u64 keys over [s, e). Runs are same-bucket
// (avg <=1); correctness holds for ANY length. Lanes own disjoint ranges.
__device__ __forceinline__ void sort_run(unsigned long long* __restrict__ srt,
                                         int s, int e) {
    for (int i = s + 1; i < e; ++i) {
        const unsigned long long key = srt[i];
        int q = i - 1;
        while (q >= s && srt[q] > key) {
            srt[q + 1] = srt[q];
            --q;
        }
        srt[q + 1] = key;
    }
}

// ---------------------------------------------------------------------------
// FAST PATH (R10): single-atomic-phase counting sort, n <= MAXC*64 (always
// true for this geometry, max ring ~703).
//
// Key change vs R9 (rocprof: null result from guards/occupancy -> per-wave
// chain + instruction count is the limiter, not occupancy): the pass-A
// histogram atomic RETURNS the element's within-bucket arrival rank (old).
// Caching it kills the entire second atomic round: pass B is
//   pos = start[bk] (plain ds_read) + old.
// Cleanup run-ends are start+count with both in registers (deletes the
// 8-way-bank-conflicted strided hist reads), and the whole cleanup phase +
// fence is wave-skipped when no bucket holds >=2 keys.
//
// Key order = (prand_bits, j), j = compact index ascending == pixel ascending
// among selected -> identical stable tie-break as jax argsort (verified
// R4/R7/R8). Returns k; if k > CAP caller defers to the overflow kernel.
// ---------------------------------------------------------------------------
template <int CAP>
__device__ int gather_count_sort(
    int b, int d, int lane, int n,
    const float* __restrict__ img, const unsigned char* __restrict__ selb,
    const float* __restrict__ prand, float* __restrict__ out,
    const unsigned short* __restrict__ ring_pix,
    unsigned long long* __restrict__ srt, unsigned* __restrict__ hist,
    float* __restrict__ vlds) {
    const float* imgb = img + (size_t)b * HW;
    const unsigned char* sbb = selb + (size_t)b * HWB;
    const float* prb = prand + ((size_t)b * NUM_ROWS + d) * NUM_COLS;
    float* outb = out + (size_t)b * HW;
    const unsigned long long ltmask = (1ull << lane) - 1ull;
    const unsigned short* rp = ring_pix + d * NUM_COLS;

    // zero histogram (wave-private region)
#pragma unroll
    for (int t = 0; t < WPL; ++t) hist[t * 64 + lane] = 0;

    // Batched guarded loads (all L2-hot or coalesced); n is wave-uniform.
    int p[MAXC];
    unsigned char sb[MAXC];
    unsigned kb[MAXC];
#pragma unroll
    for (int c = 0; c < MAXC; ++c)
        if (c * 64 < n) p[c] = rp[min(c * 64 + lane, n - 1)];
#pragma unroll
    for (int c = 0; c < MAXC; ++c)
        if (c * 64 < n) sb[c] = sbb[p[c] >> 3];
#pragma unroll
    for (int c = 0; c < MAXC; ++c)
        if (c * 64 < n) kb[c] = __float_as_uint(prb[c * 64 + lane]);

    unsigned selm = 0;
#pragma unroll
    for (int c = 0; c < MAXC; ++c)
        if (c * 64 < n) {
            if ((c * 64 + lane) < n && ((sb[c] >> (p[c] & 7)) & 1)) selm |= 1u << c;
        }

    // Selected-only img gather in arc order; issued early so its latency
    // hides under pass A + the prefix scan. Consumed at pass B.
    float v[MAXC];
#pragma unroll
    for (int c = 0; c < MAXC; ++c)
        if (c * 64 < n) {
            if ((selm >> c) & 1) v[c] = imgb[p[c]];
        }

    lds_fence();  // hist zeroing ordered before atomics

    // Pass A: compact index via ballot (jc) + RETURNING histogram atomic
    // (oldc = within-bucket arrival rank). The only atomic phase.
    int jc[MAXC], oldc[MAXC];
    int base = 0;
#pragma unroll
    for (int c = 0; c < MAXC; ++c)
        if (c * 64 < n) {
            const bool sel = (selm >> c) & 1;
            const unsigned long long ball = __ballot(sel);
            if (sel) {
                jc[c] = base + __popcll(ball & ltmask);
                const int bk = (int)(__uint_as_float(kb[c]) * (float)NBUCK);
                const unsigned sh = (unsigned)((bk & 1) * 16);
                const unsigned old = atomicAdd(&hist[bk >> 1], 1u << sh);
                oldc[c] = (int)((old >> sh) & 0xffffu);
            }
            base += __popcll(ball);
        }
    const int k = base;
    if (k > CAP) return k;  // deep binomial tail: caller defers
    if (k == 0) return 0;

    lds_fence();  // histogram counts visible

    // Exclusive prefix over NBUCK buckets (packed halfword pairs). Counts
    // (cw) and starts (stw) stay in registers for the cleanup phase.
    unsigned cw[WPL], stw[WPL];
    unsigned run = 0;
#pragma unroll
    for (int t = 0; t < WPL; ++t) {
        const unsigned w = hist[lane * WPL + t];
        cw[t] = w;
        const unsigned c0 = w & 0xffffu;
        stw[t] = run | ((run + c0) << 16);
        run += c0 + (w >> 16);
    }
    const unsigned own = run;
#pragma unroll
    for (int off = 1; off < 64; off <<= 1) {
        const unsigned o = __shfl_up(run, off, 64);
        if (lane >= off) run += o;
    }
    const unsigned bx = run - own;
    const unsigned bxp = bx | (bx << 16);
#pragma unroll
    for (int t = 0; t < WPL; ++t) {
        stw[t] += bxp;
        hist[lane * WPL + t] = stw[t];  // publish starts for pass B
    }

    lds_fence();  // starts visible

    // Pass B: pos = start (plain read) + old. No atomics, no cursor update.
#pragma unroll
    for (int c = 0; c < MAXC; ++c)
        if (c * 64 < n) {
            if ((selm >> c) & 1) {
                const int bk = (int)(__uint_as_float(kb[c]) * (float)NBUCK);
                const unsigned sh = (unsigned)((bk & 1) * 16);
                const int pos = (int)((hist[bk >> 1] >> sh) & 0xffffu) + oldc[c];
                srt[pos] = ((unsigned long long)kb[c] << 16) | (unsigned)jc[c];
                vlds[jc[c]] = v[c];
            }
        }

    lds_fence();  // scatter complete

    // Cleanup: only needed if some bucket has >=2 keys (ends/starts from
    // registers). Wave-uniform skip of the whole phase + fence otherwise.
    bool any2 = false;
#pragma unroll
    for (int t = 0; t < WPL; ++t)
        if ((cw[t] & 0xffffu) >= 2 || (cw[t] >> 16) >= 2) any2 = true;
    if (__ballot(any2) != 0ull) {
#pragma unroll
        for (int t = 0; t < WPL; ++t) {
            const unsigned s0 = stw[t] & 0xffffu, c0 = cw[t] & 0xffffu;
            const unsigned s1 = stw[t] >> 16, c1 = cw[t] >> 16;
            if (c0 >= 2) sort_run(srt, (int)s0, (int)(s0 + c0));
            if (c1 >= 2) sort_run(srt, (int)s1, (int)(s1 + c1));
        }
        lds_fence();  // sorted keys visible
    }

    // Epilogue: compact slot q receives the value of the rank-q element:
    // out[p_q] = vlds[srt_j[q]] (two pipelined LDS reads, arc-order stores).
    const unsigned short* s16 = (const unsigned short*)srt;
#pragma unroll
    for (int c = 0; c < MAXC; ++c)
        if (c * 64 < n) {
            if ((selm >> c) & 1) {
                const int jp = s16[4 * jc[c]];  // low 16 bits of key q
                outb[p[c]] = vlds[jp];
            }
        }
    return k;
}

// ---------------------------------------------------------------------------
// SLOW PATH (defensive, n > MAXC*64 — geometrically impossible here but kept
// per the R6 lesson; wave-uniform branch, never taken in practice). R9's
// verified two-atomic-phase logic with fully dynamic chunk loops.
// ---------------------------------------------------------------------------
template <int CAP>
__device__ int gather_count_sort_dyn(
    int b, int d, int lane, int n,
    const float* __restrict__ img, const unsigned char* __restrict__ selb,
    const float* __restrict__ prand, float* __restrict__ out,
    const unsigned short* __restrict__ ring_pix,
    unsigned long long* __restrict__ srt, unsigned* __restrict__ hist,
    float* __restrict__ vlds) {
    const float* imgb = img + (size_t)b * HW;
    const unsigned char* sbb = selb + (size_t)b * HWB;
    const float* prb = prand + ((size_t)b * NUM_ROWS + d) * NUM_COLS;
    float* outb = out + (size_t)b * HW;
    const unsigned long long ltmask = (1ull << lane) - 1ull;
    const unsigned short* rp = ring_pix + d * NUM_COLS;

    for (int t = 0; t < WPL; ++t) hist[t * 64 + lane] = 0;
    lds_fence();

    // Pass A: count + vlds fill.
    int base = 0;
    for (int c0 = 0; c0 < n; c0 += 64) {
        const int i = c0 + lane;
        bool sel = false;
        int pp = 0;
        unsigned kk = 0;
        if (i < n) {
            pp = rp[i];
            kk = __float_as_uint(prb[min(i, NUM_COLS - 1)]);
            sel = (sbb[pp >> 3] >> (pp & 7)) & 1;
        }
        const unsigned long long ball = __ballot(sel);
        if (sel) {
            const int j = base + __popcll(ball & ltmask);
            if (j < CAP) vlds[j] = imgb[pp];
            const int bk = (int)(__uint_as_float(kk) * (float)NBUCK);
            atomicAdd(&hist[bk >> 1], 1u << ((bk & 1) * 16));
        }
        base += __popcll(ball);
    }
    const int k = base;
    if (k > CAP) return k;
    if (k == 0) return 0;
    lds_fence();

    // Scan (starts to LDS, st kept in regs).
    unsigned neww[WPL];
    unsigned run = 0;
    for (int t = 0; t < WPL; ++t) {
        const unsigned w = hist[lane * WPL + t];
        const unsigned c0 = w & 0xffffu;
        neww[t] = run | ((run + c0) << 16);
        run += c0 + (w >> 16);
    }
    const unsigned own = run;
    for (int off = 1; off < 64; off <<= 1) {
        const unsigned o = __shfl_up(run, off, 64);
        if (lane >= off) run += o;
    }
    const unsigned bx = run - own;
    const unsigned bxp = bx | (bx << 16);
    unsigned st[WPL];
    for (int t = 0; t < WPL; ++t) {
        st[t] = neww[t] + bxp;
        hist[lane * WPL + t] = st[t];
    }
    lds_fence();

    // Pass B: cursor atomics (replay ballots).
    int jb = 0;
    for (int c0 = 0; c0 < n; c0 += 64) {
        const int i = c0 + lane;
        bool sel = false;
        unsigned kk = 0;
        if (i < n) {
            const int pp = rp[i];
            kk = __float_as_uint(prb[min(i, NUM_COLS - 1)]);
            sel = (sbb[pp >> 3] >> (pp & 7)) & 1;
        }
        const unsigned long long ball = __ballot(sel);
        if (sel) {
            const int j = jb + __popcll(ball & ltmask);
            const int bk = (int)(__uint_as_float(kk) * (float)NBUCK);
            const unsigned sh = (unsigned)((bk & 1) * 16);
            const unsigned old = atomicAdd(&hist[bk >> 1], 1u << sh);
            const int pos = (int)((old >> sh) & 0xffffu);
            srt[pos] = ((unsigned long long)kk << 16) | (unsigned)j;
        }
        jb += __popcll(ball);
    }
    lds_fence();

    // Cleanup (ends from post-pass-B cursors).
    for (int t = 0; t < WPL; ++t) {
        const unsigned wend = hist[lane * WPL + t];
        const unsigned ws0 = st[t];
        sort_run(srt, (int)(ws0 & 0xffffu), (int)(wend & 0xffffu));
        sort_run(srt, (int)(ws0 >> 16), (int)(wend >> 16));
    }
    lds_fence();

    // Epilogue (replay ballots).
    const unsigned short* s16 = (const unsigned short*)srt;
    jb = 0;
    for (int c0 = 0; c0 < n; c0 += 64) {
        const int i = c0 + lane;
        bool sel = false;
        int pp = 0;
        if (i < n) {
            pp = rp[i];
            sel = (sbb[pp >> 3] >> (pp & 7)) & 1;
        }
        const unsigned long long ball = __ballot(sel);
        if (sel) {
            const int j = jb + __popcll(ball & ltmask);
            const int jp = s16[4 * j];
            outb[pp] = vlds[jp];
        }
        jb += __popcll(ball);
    }
    return k;
}

// ---------------------------------------------------------------------------
// Main: one WAVE per (batch, ring); 4 waves/block; XCD-swizzled (16 whole
// images per XCD). No block barriers — waves fully independent.
// LDS: 4 x (4K srt + 1K hist + 2K vlds) = 28 KB -> 5 blocks/CU.
// ---------------------------------------------------------------------------
__global__ __launch_bounds__(256, 5) void radial_shuffle(
    const float* __restrict__ img, const unsigned char* __restrict__ selb,
    const float* __restrict__ prand, float* __restrict__ out,
    const unsigned short* __restrict__ ring_pix, const int* __restrict__ ring_cnt,
    int* __restrict__ ovf_cnt, int* __restrict__ ovf_list) {
    const int tid = threadIdx.x;
    const int wid = tid >> 6;
    const int lane = tid & 63;
    const int xcd = blockIdx.x & 7;
    const int g = (blockIdx.x >> 3) * 4 + wid;  // 0..2543 within XCD
    const int b = xcd * (BATCH / 8) + g / NUM_ROWS;
    const int d = g % NUM_ROWS;
    const int n = __builtin_amdgcn_readfirstlane(ring_cnt[d]);  // uniform branches

    __shared__ unsigned long long srt_s[4][512];  // 16 KB
    __shared__ unsigned hist_s[4][NHWORDS];       // 4 KB
    __shared__ float vl_s[4][512];                // 8 KB

    int k;
    if (n <= MAXC * 64) {
        k = gather_count_sort<512>(b, d, lane, n, img, selb, prand, out,
                                   ring_pix, srt_s[wid], hist_s[wid], vl_s[wid]);
    } else {
        k = gather_count_sort_dyn<512>(b, d, lane, n, img, selb, prand, out,
                                       ring_pix, srt_s[wid], hist_s[wid],
                                       vl_s[wid]);
    }

    if (k > 512) {
        // deep binomial tail: defer to overflow kernel
        if (lane == 0) {
            const int idx = atomicAdd(ovf_cnt, 1);
            if (idx < OVF_CAP) ovf_list[idx] = b * NUM_ROWS + d;
        }
    }
}

// Cold path: rings with k > 512 (capacity 1024 >= any ring).
__global__ __launch_bounds__(64) void overflow_sort(
    const float* __restrict__ img, const unsigned char* __restrict__ selb,
    const float* __restrict__ prand, float* __restrict__ out,
    const unsigned short* __restrict__ ring_pix, const int* __restrict__ ring_cnt,
    const int* __restrict__ ovf_cnt, const int* __restrict__ ovf_list) {
    __shared__ unsigned long long srt[1024];  // 8 KB
    __shared__ unsigned hist[NHWORDS];        // 1 KB
    __shared__ float vlds[1024];              // 4 KB
    const int m = min(*ovf_cnt, OVF_CAP);
    const int lane = threadIdx.x;
    for (int t = blockIdx.x; t < m; t += gridDim.x) {
        const int bd = ovf_list[t];
        const int b = bd / NUM_ROWS;
        const int d = bd % NUM_ROWS;
        const int n = __builtin_amdgcn_readfirstlane(ring_cnt[d]);
        if (n <= MAXC * 64) {
            gather_count_sort<1024>(b, d, lane, n, img, selb, prand, out,
                                    ring_pix, srt, hist, vlds);
        } else {
            gather_count_sort_dyn<1024>(b, d, lane, n, img, selb, prand, out,
                                        ring_pix, srt, hist, vlds);
        }
        __syncthreads();  // before LDS reuse (single wave: cheap)
    }
}

extern "C" void kernel_launch(void* const* d_in, const int* in_sizes, int n_in,
                              void* d_out, int out_size, void* d_ws, size_t ws_size,
                              hipStream_t stream) {
    const float* img   = (const float*)d_in[0];  // (128,224,224,1) f32
    const float* mask  = (const float*)d_in[1];  // (128,224,224)   f32
    const float* prand = (const float*)d_in[2];  // (128,159,1024)  f32
    float* out = (float*)d_out;                  // (128,224,224,1) f32

    // Workspace layout (~1.15 MB total):
    unsigned short* ring_pix = (unsigned short*)d_ws;  // 159*1024 u16
    int* ring_cnt = (int*)((char*)d_ws + NUM_ROWS * NUM_COLS * sizeof(unsigned short));
    int* ovf_cnt  = ring_cnt + NUM_ROWS;
    int* ovf_list = ovf_cnt + 1;
    unsigned char* selb = (unsigned char*)(ovf_list + OVF_CAP);  // BATCH*HWB bytes

    hipLaunchKernelGGL(pre_pass, dim3(NUM_ROWS + BATCH * HW / 8 / 256), dim3(256),
                       0, stream, (const float4*)img, (const float4*)mask,
                       (float4*)out, selb, ring_pix, ring_cnt, ovf_cnt);
    hipLaunchKernelGGL(radial_shuffle, dim3(BATCH * NUM_ROWS / 4), dim3(256), 0,
                       stream, img, selb, prand, out, ring_pix, ring_cnt,
                       ovf_cnt, ovf_list);
    hipLaunchKernelGGL(overflow_sort, dim3(16), dim3(64), 0, stream,
                       img, selb, prand, out, ring_pix, ring_cnt,
                       ovf_cnt, ovf_list);
}